// Round 1
// baseline (653.083 us; speedup 1.0000x reference)
//
#include <hip/hip_runtime.h>

// GraphVAE: GCN-VAE encoder + edge decoder + 50-iter MPM fixed point, fused
// into ONE persistent 20-block kernel.
//
// Round-1 change: the kernel is latency-bound on 53 device-wide barriers
// (~7.5us each; VALUBusy 0.8%, HBM 0.5%). The 50 MPM-loop barriers are
// replaced by a single-round-trip protocol:
//   * all cross-block MPM data (X ping-pong, per-block partial ||Xn||^2)
//     moves through agent-scope RELAXED atomics (cache-bypass to the
//     coherence point) -> no buffer_wbl2 / buffer_inv in the loop at all.
//   * block p's partial sum-of-squares (strictly >0) is stored into a
//     per-iteration slot flags[t][p]; the slot doubles as the arrival flag
//     (0 = not arrived). Wave 0 polls the 20 slots with relaxed loads and
//     reduces them -> barrier + norm reduction in ONE MALL round trip.
//   * ordering: the __syncthreads before the flag store drains every
//     wave's vmcnt (compiler-emitted s_waitcnt vmcnt(0) before s_barrier),
//     plus an explicit vmcnt(0) in the storing lane.
// Encoder keeps its 3 release/acquire barriers (plain-stored hT/h2T/Bm need
// the L2 writeback) but polls RELAXED with one trailing ACQUIRE instead of
// an L2-invalidating acquire per spin.

#define NN 80
#define PBLK 20            // blocks (each owns 4 columns of X) - all co-resident
#define TPB 320            // 5 full waves; lane <-> one (i,a) output
#define RP 84              // LDS row pad: 84 mod 32 = 20 -> conflict-free b128
#define NCOLS 13           // max owned feature columns per block (256/20 rounded up)
#define AGT __HIP_MEMORY_SCOPE_AGENT

__device__ __forceinline__ void gbar(int* ctr, int target){
  __syncthreads();
  if (threadIdx.x == 0){
    __hip_atomic_fetch_add(ctr, 1, __ATOMIC_RELEASE, AGT);
    while (__hip_atomic_load(ctr, __ATOMIC_RELAXED, AGT) < target)
      __builtin_amdgcn_s_sleep(1);
    (void)__hip_atomic_load(ctr, __ATOMIC_ACQUIRE, AGT);  // one inv, not per-poll
  }
  __syncthreads();
}

__device__ __forceinline__ float wave_sum(float v){
  #pragma unroll
  for (int k = 32; k >= 1; k >>= 1) v += __shfl_xor(v, k, 64);
  return v;
}

// GCN aggregate (+self loop) + bias + BatchNorm(train, biased var) + ReLU for
// this block's owned feature columns. inL: LDS [NCOLS][80] (pre-aggregation,
// own columns). outT: global transposed [256][80].
__device__ void gcn_bn_relu(const float* inL, float* outT,
                            const float* bias, const float* gamma, const float* beta,
                            const int* ei, const float* dinv,
                            float* accL, float* colstat, int p, int tid)
{
  for (int u = tid; u < NCOLS*NN; u += TPB) accL[u] = 0.f;
  __syncthreads();
  for (int cl = 0; cl < NCOLS; cl++){
    int c = p + PBLK*cl; if (c >= 256) break;
    const float* col = &inL[cl*NN];
    for (int e = tid; e < 800; e += TPB){
      int sidx = ei[e], didx = ei[800+e];
      atomicAdd(&accL[cl*NN + didx], col[sidx]*dinv[sidx]*dinv[didx]);
    }
  }
  __syncthreads();
  for (int u = tid; u < NCOLS*NN; u += TPB){
    int cl = u/NN, i = u - cl*NN, c = p + PBLK*cl;
    if (c < 256) accL[u] += inL[cl*NN+i]*dinv[i]*dinv[i] + bias[c];
  }
  __syncthreads();
  if (tid < NCOLS){
    int c = p + PBLK*tid;
    if (c < 256){
      const float* a = &accL[tid*NN];
      float m = 0.f;
      for (int i = 0; i < NN; i++) m += a[i];
      m *= (1.0f/NN);
      float v = 0.f;
      for (int i = 0; i < NN; i++){ float d = a[i]-m; v += d*d; }
      v *= (1.0f/NN);
      colstat[2*tid]   = m;
      colstat[2*tid+1] = 1.0f/sqrtf(v + 1e-5f);
    }
  }
  __syncthreads();
  for (int u = tid; u < NCOLS*NN; u += TPB){
    int cl = u/NN, i = u - cl*NN, c = p + PBLK*cl;
    if (c < 256){
      float hv = gamma[c]*(accL[u]-colstat[2*cl])*colstat[2*cl+1] + beta[c];
      outT[c*NN+i] = fmaxf(hv, 0.f);
    }
  }
}

__global__ __launch_bounds__(TPB, 1) void gvae_fused(
    const float* __restrict__ x,  const int* __restrict__ ei, const int* __restrict__ adj,
    const float* __restrict__ eps,
    const float* __restrict__ W1, const float* __restrict__ b1, const float* __restrict__ g1, const float* __restrict__ bt1,
    const float* __restrict__ W2, const float* __restrict__ b2, const float* __restrict__ g2, const float* __restrict__ bt2,
    const float* __restrict__ Wmu,const float* __restrict__ bmu,const float* __restrict__ Wlv,const float* __restrict__ blv,
    const float* __restrict__ We1,const float* __restrict__ be1,const float* __restrict__ We2,const float* __restrict__ be2,
    float* __restrict__ out, float* __restrict__ ws)
{
  const int tid = threadIdx.x;
  const int p   = blockIdx.x;

  // workspace layout (floats)
  int*   ctr   = (int*)ws;        // [0]       encoder barrier counter (memset 0)
  float* flags = ws + 32;         // [50*32]   per-iter per-block partial ||Xn||^2 (memset 0)
  float* hT    = ws + 2048;       // [256*80]  layer-1 output, transposed
  float* h2T   = hT  + 20480;     // [256*80]  layer-2 output, transposed
  float* Bm    = h2T + 20480;     // [80*80]   B = sigmoid(A_hat), diag=1
  float* Xb0   = Bm  + 6400;      // [80*80]   MPM ping
  float* Xb1   = Xb0 + 6400;      // [80*80]   MPM pong

  __shared__ float Xs[NN*RP];        // MPM: X tile (row pad 84)
  __shared__ float MtL[4*RP];        // MPM: M^T (own 4 columns)
  __shared__ float red[8];
  __shared__ float dinv[NN];
  __shared__ float accL[NCOLS*NN];
  __shared__ float hL[NCOLS*NN];     // own-column staging between GEMM and GCN
  __shared__ float gv[256], zv[128], t1v[256];
  __shared__ float colstat[2*NCOLS];

  // ---------------- E0: degrees (redundant per block) + GEMM1 x@W1 ----------
  for (int i = tid; i < NN; i += TPB) accL[i] = 1.0f;           // self loop
  __syncthreads();
  for (int e = tid; e < 800; e += TPB) atomicAdd(&accL[ei[800+e]], 1.0f);
  __syncthreads();
  for (int i = tid; i < NN; i += TPB) dinv[i] = 1.0f/sqrtf(accL[i]);
  __syncthreads();

  for (int u = tid; u < NCOLS*NN; u += TPB){
    int cl = u/NN, i = u - cl*NN, c = p + PBLK*cl;
    if (c < 256){
      float s = 0.f;
      for (int k = 0; k < 64; k++) s += x[i*64+k]*W1[k*256+c];
      hL[u] = s;
    }
  }
  __syncthreads();
  gcn_bn_relu(hL, hT, b1, g1, bt1, ei, dinv, accL, colstat, p, tid);
  gbar(ctr, 1*PBLK);                                   // hT complete (all cols)

  // ---------------- E2: GEMM2 h@W2 (reads all cols of hT) -------------------
  for (int u = tid; u < 20*NCOLS; u += TPB){
    int cl = u/20, iq = u - cl*20, c = p + PBLK*cl;
    if (c < 256){
      int i0 = 4*iq;
      float a0=0.f,a1=0.f,a2=0.f,a3=0.f;
      for (int k = 0; k < 256; k++){
        float wv = W2[k*256+c];
        float4 hv = *(const float4*)&hT[k*NN+i0];
        a0 += hv.x*wv; a1 += hv.y*wv; a2 += hv.z*wv; a3 += hv.w*wv;
      }
      hL[cl*NN+i0+0]=a0; hL[cl*NN+i0+1]=a1; hL[cl*NN+i0+2]=a2; hL[cl*NN+i0+3]=a3;
    }
  }
  __syncthreads();
  gcn_bn_relu(hL, h2T, b2, g2, bt2, ei, dinv, accL, colstat, p, tid);
  gbar(ctr, 2*PBLK);                                   // h2T complete

  // ---------------- E4: pool -> z -> t1 -> pair logits -> B -----------------
  for (int c = tid; c < 256; c += TPB){
    const float* r = &h2T[c*NN];
    float s = 0.f;
    for (int i = 0; i < NN; i++) s += r[i];
    gv[c] = s*(1.0f/NN);
  }
  __syncthreads();
  for (int c = tid; c < 128; c += TPB){
    float smu = bmu[c], slv = blv[c];
    for (int k = 0; k < 256; k++){
      float g = gv[k];
      smu += g*Wmu[k*128+c];
      slv += g*Wlv[k*128+c];
    }
    slv = fminf(fmaxf(slv, -4.f), 4.f);
    zv[c] = smu + eps[c]*expf(0.5f*slv);
  }
  __syncthreads();
  for (int c = tid; c < 256; c += TPB){
    float s = be1[c];
    for (int k = 0; k < 128; k++) s += zv[k]*We1[k*256+c];
    t1v[c] = fmaxf(s, 0.f);
  }
  __syncthreads();
  for (int r = 0; r < 4; r++){
    int i = p + PBLK*r;                                // rows p, p+20, p+40, p+60
    if (tid == 0) Bm[i*NN+i] = 1.0f;                   // diag forced to 1
    for (int j = i+1+tid; j < NN; j += TPB){
      int off = i*(2*NN-1-i)/2 + (j-i-1);              // triu(k=1) flat index
      float s = be2[off];
      for (int k = 0; k < 256; k++) s += t1v[k]*We2[k*3160+off];
      float sg = 1.0f/(1.0f + expf(-s));
      Bm[i*NN+j] = sg;
      Bm[j*NN+i] = sg;
    }
  }
  gbar(ctr, 3*PBLK);                                   // Bm complete

  // ---------------- E5: per-lane register caches for the MPM loop -----------
  const int w  = tid >> 6;
  const int l  = tid & 63;
  const int il = 16*w + (l & 15);    // this lane's row i (== j in M phase)
  const int ae = l >> 4;             // local column index 0..3
  const int al = 4*p + ae;           // this lane's column a

  float4 Af[20], Bf[20];
  float degA = 0.f, degB = 0.f;
  #pragma unroll
  for (int c = 0; c < 20; c++){
    int j0 = 4*c;
    int4 ar = *(const int4*)&adj[il*NN+j0];
    int q0 = adj[(j0+0)*NN+il];
    int q1 = adj[(j0+1)*NN+il];
    int q2 = adj[(j0+2)*NN+il];
    int q3 = adj[(j0+3)*NN+il];
    float4 a;
    a.x = ((ar.x|q0) != 0 || il == j0+0) ? 1.f : 0.f;
    a.y = ((ar.y|q1) != 0 || il == j0+1) ? 1.f : 0.f;
    a.z = ((ar.z|q2) != 0 || il == j0+2) ? 1.f : 0.f;
    a.w = ((ar.w|q3) != 0 || il == j0+3) ? 1.f : 0.f;
    Af[c] = a;
    degA += (a.x+a.y)+(a.z+a.w);
  }
  #pragma unroll
  for (int c = 0; c < 20; c++){
    float4 b = *(const float4*)&Bm[al*NN+4*c];
    Bf[c] = b;
    degB += (b.x+b.y)+(b.z+b.w);
  }
  const float ns = 1.0f/(fabsf(degA-degB)+1.0f);
  // b==a exclusion: zero B[a][a] in the register cache (valid since X,B >= 0)
  #pragma unroll
  for (int c = 0; c < 20; c++){
    if (c == p){
      if      (ae == 0) Bf[c].x = 0.f;
      else if (ae == 1) Bf[c].y = 0.f;
      else if (ae == 2) Bf[c].z = 0.f;
      else              Bf[c].w = 0.f;
    }
  }

  // ---------------- MPM: 50 iterations, 1 MALL round trip each --------------
  for (int u = tid; u < NN*RP; u += TPB) Xs[u] = 1.0f/NN;   // X0 = 1/n
  float xn = 0.f;
  float sc = 1.0f;                    // 1/||R_{t-1}|| applied one step late
  for (int t = 0; t < 50; t++){
    __syncthreads();                  // Xs staged (t=0: init) visible

    // M[il][al] = max_{b != al} X[il][b]*B[al][b]
    float m = 0.f;
    #pragma unroll
    for (int c = 0; c < 20; c++){
      float4 xv = *(const float4*)&Xs[il*RP+4*c];
      float p0 = xv.x*Bf[c].x, p1 = xv.y*Bf[c].y, p2 = xv.z*Bf[c].z, p3 = xv.w*Bf[c].w;
      m = fmaxf(m, fmaxf(fmaxf(p0,p1), fmaxf(p2,p3)));
    }
    float xnode = Xs[il*RP+al];
    MtL[ae*RP+il] = m;
    __syncthreads();

    // edge[il][al] = sum_j A[il][j]*M[j][al] - M[il][al]   (A[i][i] = 1)
    float e0=0.f,e1=0.f,e2=0.f,e3=0.f;
    #pragma unroll
    for (int c = 0; c < 20; c++){
      float4 mv = *(const float4*)&MtL[ae*RP+4*c];
      e0 += Af[c].x*mv.x; e1 += Af[c].y*mv.y; e2 += Af[c].z*mv.z; e3 += Af[c].w*mv.w;
    }
    float edge = ((e0+e1)+(e2+e3)) - m;
    xn = sc*(ns*xnode + edge);        // R_{t+1} = f(R_t / ||R_t||)

    if (t < 49){
      float* Xdst = (t&1) ? Xb1 : Xb0;
      // relaxed agent atomic store: bypasses local caches -> visible at the
      // coherence point without any wbl2/inv.
      __hip_atomic_store(&Xdst[il*NN+al], xn, __ATOMIC_RELAXED, AGT);
    }
    float v = wave_sum(xn*xn);
    if (l == 0) red[w] = v;
    __syncthreads();                  // red[] ready; every wave's vmem drained
                                      // (compiler emits s_waitcnt vmcnt(0)
                                      //  before s_barrier)

    if (w == 0){
      float part = ((red[0]+red[1])+(red[2]+red[3]))+red[4];   // > 0 always
      if (l == 0){
        asm volatile("s_waitcnt vmcnt(0)" ::: "memory");
        __hip_atomic_store(&flags[t*32+p], part, __ATOMIC_RELAXED, AGT);
      }
      // arrival + reduction in one round trip: lanes 0..19 poll the slots
      float fv = 0.f;
      for (;;){
        if (l < 20 && fv == 0.f)
          fv = __hip_atomic_load(&flags[t*32+l], __ATOMIC_RELAXED, AGT);
        if (__all((l >= 20) || (fv != 0.f))) break;
      }
      float tot = wave_sum((l < 20) ? fv : 0.f);
      if (l == 0) red[5] = tot;       // ||R_{t+1}||^2, deterministic order
    }
    __syncthreads();                  // tot ready; all blocks' X stores visible
    sc = 1.0f/sqrtf(red[5]);

    if (t < 49){
      const float* Xsrc = (t&1) ? Xb1 : Xb0;
      for (int u = tid; u < NN*NN; u += TPB){
        int j = u/NN, c = u - j*NN;
        // relaxed agent atomic load: served at the coherence point, cannot
        // hit a stale local L1/L2 line.
        Xs[j*RP+c] = __hip_atomic_load((float*)&Xsrc[u], __ATOMIC_RELAXED, AGT);
      }
    }
  }
  out[il*NN+al] = xn*sc;              // final normalization
}

extern "C" void kernel_launch(void* const* d_in, const int* in_sizes, int n_in,
                              void* d_out, int out_size, void* d_ws, size_t ws_size,
                              hipStream_t stream)
{
  (void)in_sizes; (void)n_in; (void)out_size; (void)ws_size;
  // zero barrier counter + 50x32 flag slots (re-poisoned to 0xAA before launch)
  hipMemsetAsync(d_ws, 0, 8192, stream);
  gvae_fused<<<PBLK, TPB, 0, stream>>>(
      (const float*)d_in[0],  (const int*)d_in[1],   (const int*)d_in[2],   (const float*)d_in[3],
      (const float*)d_in[4],  (const float*)d_in[5],  (const float*)d_in[6],  (const float*)d_in[7],
      (const float*)d_in[8],  (const float*)d_in[9],  (const float*)d_in[10], (const float*)d_in[11],
      (const float*)d_in[12], (const float*)d_in[13], (const float*)d_in[14], (const float*)d_in[15],
      (const float*)d_in[16], (const float*)d_in[17], (const float*)d_in[18], (const float*)d_in[19],
      (float*)d_out, (float*)d_ws);
}

// Round 2
// 482.586 us; speedup vs baseline: 1.3533x; 1.3533x over previous
//
#include <hip/hip_runtime.h>

// GraphVAE: GCN-VAE encoder + edge decoder + 50-iter MPM fixed point, fused
// into ONE persistent 20-block kernel.
//
// Round-2 exchange protocol (fixing round-1's three regressions):
//  * X exchange buffer is COLUMN-major: each block's 320 values are a
//    contiguous 1.25KB run. Stores are staged through LDS and issued as 160
//    coalesced agent-relaxed u64 stores (10 lines) -> cheap vmcnt drain.
//    (round-1: 320 scattered uncached dwords)
//  * per-block flag slots padded to 64B each; pollers latch + s_sleep(1)
//    backoff -> no same-line contention at the coherence point.
//    (round-1: 400 continuous pollers on one line starved the flag stores)
//  * reload: ONE acquire load (buffer_inv L1+L2, round-0-proven) then plain
//    cached float4 loads + LDS transpose. Stores were uncached, so L2 never
//    holds dirty X lines; the single inv clears stale read-side copies.
//    (round-1: 6400 uncached scalar atomic loads per block)
//  * still NO wbl2 release in the loop, flag value doubles as the norm
//    partial (barrier + reduction in one round trip), deterministic sum.

#define NN 80
#define PBLK 20            // blocks (each owns 4 columns of X) - all co-resident
#define TPB 320            // 5 full waves; lane <-> one (i,a) output
#define RP 84              // LDS row pad: conflict-free b128 row reads
#define NCOLS 13           // max owned feature columns per block (256/20 rounded up)
#define FSTR 16            // flag slot stride in dwords (64B per slot)
#define AGT __HIP_MEMORY_SCOPE_AGENT

__device__ __forceinline__ void gbar(int* ctr, int target){
  __syncthreads();
  if (threadIdx.x == 0){
    __hip_atomic_fetch_add(ctr, 1, __ATOMIC_RELEASE, AGT);
    while (__hip_atomic_load(ctr, __ATOMIC_RELAXED, AGT) < target)
      __builtin_amdgcn_s_sleep(1);
    (void)__hip_atomic_load(ctr, __ATOMIC_ACQUIRE, AGT);  // one inv, not per-poll
  }
  __syncthreads();
}

__device__ __forceinline__ float wave_sum(float v){
  #pragma unroll
  for (int k = 32; k >= 1; k >>= 1) v += __shfl_xor(v, k, 64);
  return v;
}

// GCN aggregate (+self loop) + bias + BatchNorm(train, biased var) + ReLU for
// this block's owned feature columns. inL: LDS [NCOLS][80] (pre-aggregation,
// own columns). outT: global transposed [256][80].
__device__ void gcn_bn_relu(const float* inL, float* outT,
                            const float* bias, const float* gamma, const float* beta,
                            const int* ei, const float* dinv,
                            float* accL, float* colstat, int p, int tid)
{
  for (int u = tid; u < NCOLS*NN; u += TPB) accL[u] = 0.f;
  __syncthreads();
  for (int cl = 0; cl < NCOLS; cl++){
    int c = p + PBLK*cl; if (c >= 256) break;
    const float* col = &inL[cl*NN];
    for (int e = tid; e < 800; e += TPB){
      int sidx = ei[e], didx = ei[800+e];
      atomicAdd(&accL[cl*NN + didx], col[sidx]*dinv[sidx]*dinv[didx]);
    }
  }
  __syncthreads();
  for (int u = tid; u < NCOLS*NN; u += TPB){
    int cl = u/NN, i = u - cl*NN, c = p + PBLK*cl;
    if (c < 256) accL[u] += inL[cl*NN+i]*dinv[i]*dinv[i] + bias[c];
  }
  __syncthreads();
  if (tid < NCOLS){
    int c = p + PBLK*tid;
    if (c < 256){
      const float* a = &accL[tid*NN];
      float m = 0.f;
      for (int i = 0; i < NN; i++) m += a[i];
      m *= (1.0f/NN);
      float v = 0.f;
      for (int i = 0; i < NN; i++){ float d = a[i]-m; v += d*d; }
      v *= (1.0f/NN);
      colstat[2*tid]   = m;
      colstat[2*tid+1] = 1.0f/sqrtf(v + 1e-5f);
    }
  }
  __syncthreads();
  for (int u = tid; u < NCOLS*NN; u += TPB){
    int cl = u/NN, i = u - cl*NN, c = p + PBLK*cl;
    if (c < 256){
      float hv = gamma[c]*(accL[u]-colstat[2*cl])*colstat[2*cl+1] + beta[c];
      outT[c*NN+i] = fmaxf(hv, 0.f);
    }
  }
}

__global__ __launch_bounds__(TPB, 1) void gvae_fused(
    const float* __restrict__ x,  const int* __restrict__ ei, const int* __restrict__ adj,
    const float* __restrict__ eps,
    const float* __restrict__ W1, const float* __restrict__ b1, const float* __restrict__ g1, const float* __restrict__ bt1,
    const float* __restrict__ W2, const float* __restrict__ b2, const float* __restrict__ g2, const float* __restrict__ bt2,
    const float* __restrict__ Wmu,const float* __restrict__ bmu,const float* __restrict__ Wlv,const float* __restrict__ blv,
    const float* __restrict__ We1,const float* __restrict__ be1,const float* __restrict__ We2,const float* __restrict__ be2,
    float* __restrict__ out, float* __restrict__ ws)
{
  const int tid = threadIdx.x;
  const int p   = blockIdx.x;

  // workspace layout (floats)
  int*   ctr   = (int*)ws;        // [0]        encoder barrier counter (memset 0)
  float* flags = ws + 64;         // [50*20*16] padded per-iter per-block flag/partial (memset 0)
  float* hT    = ws + 16384;      // [256*80]   layer-1 output, transposed
  float* h2T   = hT  + 20480;     // [256*80]   layer-2 output, transposed
  float* Bm    = h2T + 20480;     // [80*80]    B = sigmoid(A_hat), diag=1
  float* Xc0   = Bm  + 6400;      // [80*80]    MPM ping (COLUMN-major: Xc[a*80+i])
  float* Xc1   = Xc0 + 6400;      // [80*80]    MPM pong

  __shared__ float Xs[NN*RP];        // MPM: X tile, row-major [i][a], pad 84
  __shared__ float MtL[4*RP];        // MPM: M^T (own 4 columns)
  __shared__ float red[8];
  __shared__ float dinv[NN];
  __shared__ __align__(16) float accL[NCOLS*NN];   // also reused as MPM store staging
  __shared__ float hL[NCOLS*NN];     // own-column staging between GEMM and GCN
  __shared__ float gv[256], zv[128], t1v[256];
  __shared__ float colstat[2*NCOLS];

  // ---------------- E0: degrees (redundant per block) + GEMM1 x@W1 ----------
  for (int i = tid; i < NN; i += TPB) accL[i] = 1.0f;           // self loop
  __syncthreads();
  for (int e = tid; e < 800; e += TPB) atomicAdd(&accL[ei[800+e]], 1.0f);
  __syncthreads();
  for (int i = tid; i < NN; i += TPB) dinv[i] = 1.0f/sqrtf(accL[i]);
  __syncthreads();

  for (int u = tid; u < NCOLS*NN; u += TPB){
    int cl = u/NN, i = u - cl*NN, c = p + PBLK*cl;
    if (c < 256){
      float s = 0.f;
      for (int k = 0; k < 64; k++) s += x[i*64+k]*W1[k*256+c];
      hL[u] = s;
    }
  }
  __syncthreads();
  gcn_bn_relu(hL, hT, b1, g1, bt1, ei, dinv, accL, colstat, p, tid);
  gbar(ctr, 1*PBLK);                                   // hT complete (all cols)

  // ---------------- E2: GEMM2 h@W2 (reads all cols of hT) -------------------
  for (int u = tid; u < 20*NCOLS; u += TPB){
    int cl = u/20, iq = u - cl*20, c = p + PBLK*cl;
    if (c < 256){
      int i0 = 4*iq;
      float a0=0.f,a1=0.f,a2=0.f,a3=0.f;
      for (int k = 0; k < 256; k++){
        float wv = W2[k*256+c];
        float4 hv = *(const float4*)&hT[k*NN+i0];
        a0 += hv.x*wv; a1 += hv.y*wv; a2 += hv.z*wv; a3 += hv.w*wv;
      }
      hL[cl*NN+i0+0]=a0; hL[cl*NN+i0+1]=a1; hL[cl*NN+i0+2]=a2; hL[cl*NN+i0+3]=a3;
    }
  }
  __syncthreads();
  gcn_bn_relu(hL, h2T, b2, g2, bt2, ei, dinv, accL, colstat, p, tid);
  gbar(ctr, 2*PBLK);                                   // h2T complete

  // ---------------- E4: pool -> z -> t1 -> pair logits -> B -----------------
  for (int c = tid; c < 256; c += TPB){
    const float* r = &h2T[c*NN];
    float s = 0.f;
    for (int i = 0; i < NN; i++) s += r[i];
    gv[c] = s*(1.0f/NN);
  }
  __syncthreads();
  for (int c = tid; c < 128; c += TPB){
    float smu = bmu[c], slv = blv[c];
    for (int k = 0; k < 256; k++){
      float g = gv[k];
      smu += g*Wmu[k*128+c];
      slv += g*Wlv[k*128+c];
    }
    slv = fminf(fmaxf(slv, -4.f), 4.f);
    zv[c] = smu + eps[c]*expf(0.5f*slv);
  }
  __syncthreads();
  for (int c = tid; c < 256; c += TPB){
    float s = be1[c];
    for (int k = 0; k < 128; k++) s += zv[k]*We1[k*256+c];
    t1v[c] = fmaxf(s, 0.f);
  }
  __syncthreads();
  for (int r = 0; r < 4; r++){
    int i = p + PBLK*r;                                // rows p, p+20, p+40, p+60
    if (tid == 0) Bm[i*NN+i] = 1.0f;                   // diag forced to 1
    for (int j = i+1+tid; j < NN; j += TPB){
      int off = i*(2*NN-1-i)/2 + (j-i-1);              // triu(k=1) flat index
      float s = be2[off];
      for (int k = 0; k < 256; k++) s += t1v[k]*We2[k*3160+off];
      float sg = 1.0f/(1.0f + expf(-s));
      Bm[i*NN+j] = sg;
      Bm[j*NN+i] = sg;
    }
  }
  gbar(ctr, 3*PBLK);                                   // Bm complete

  // ---------------- E5: per-lane register caches for the MPM loop -----------
  const int w  = tid >> 6;
  const int l  = tid & 63;
  const int il = 16*w + (l & 15);    // this lane's row i (== j in M phase)
  const int ae = l >> 4;             // local column index 0..3
  const int al = 4*p + ae;           // this lane's column a

  float4 Af[20], Bf[20];
  float degA = 0.f, degB = 0.f;
  #pragma unroll
  for (int c = 0; c < 20; c++){
    int j0 = 4*c;
    int4 ar = *(const int4*)&adj[il*NN+j0];
    int q0 = adj[(j0+0)*NN+il];
    int q1 = adj[(j0+1)*NN+il];
    int q2 = adj[(j0+2)*NN+il];
    int q3 = adj[(j0+3)*NN+il];
    float4 a;
    a.x = ((ar.x|q0) != 0 || il == j0+0) ? 1.f : 0.f;
    a.y = ((ar.y|q1) != 0 || il == j0+1) ? 1.f : 0.f;
    a.z = ((ar.z|q2) != 0 || il == j0+2) ? 1.f : 0.f;
    a.w = ((ar.w|q3) != 0 || il == j0+3) ? 1.f : 0.f;
    Af[c] = a;
    degA += (a.x+a.y)+(a.z+a.w);
  }
  #pragma unroll
  for (int c = 0; c < 20; c++){
    float4 b = *(const float4*)&Bm[al*NN+4*c];
    Bf[c] = b;
    degB += (b.x+b.y)+(b.z+b.w);
  }
  const float ns = 1.0f/(fabsf(degA-degB)+1.0f);
  // b==a exclusion: zero B[a][a] in the register cache (valid since X,B >= 0)
  #pragma unroll
  for (int c = 0; c < 20; c++){
    if (c == p){
      if      (ae == 0) Bf[c].x = 0.f;
      else if (ae == 1) Bf[c].y = 0.f;
      else if (ae == 2) Bf[c].z = 0.f;
      else              Bf[c].w = 0.f;
    }
  }

  // ---------------- MPM: 50 iterations ---------------------------------------
  for (int u = tid; u < NN*RP; u += TPB) Xs[u] = 1.0f/NN;   // X0 = 1/n
  float xn = 0.f;
  float sc = 1.0f;                    // 1/||R_{t-1}|| applied one step late
  for (int t = 0; t < 50; t++){
    __syncthreads();                  // Xs staged (t=0: init) visible

    // M[il][al] = max_{b != al} X[il][b]*B[al][b]
    float m = 0.f;
    #pragma unroll
    for (int c = 0; c < 20; c++){
      float4 xv = *(const float4*)&Xs[il*RP+4*c];
      float p0 = xv.x*Bf[c].x, p1 = xv.y*Bf[c].y, p2 = xv.z*Bf[c].z, p3 = xv.w*Bf[c].w;
      m = fmaxf(m, fmaxf(fmaxf(p0,p1), fmaxf(p2,p3)));
    }
    float xnode = Xs[il*RP+al];
    MtL[ae*RP+il] = m;
    __syncthreads();

    // edge[il][al] = sum_j A[il][j]*M[j][al] - M[il][al]   (A[i][i] = 1)
    float e0=0.f,e1=0.f,e2=0.f,e3=0.f;
    #pragma unroll
    for (int c = 0; c < 20; c++){
      float4 mv = *(const float4*)&MtL[ae*RP+4*c];
      e0 += Af[c].x*mv.x; e1 += Af[c].y*mv.y; e2 += Af[c].z*mv.z; e3 += Af[c].w*mv.w;
    }
    float edge = ((e0+e1)+(e2+e3)) - m;
    xn = sc*(ns*xnode + edge);        // R_{t+1} = f(R_t / ||R_t||)

    // stage xn column-major in LDS (accL reused): Xstg[ae*80 + il]
    accL[ae*NN + il] = xn;
    float v = wave_sum(xn*xn);
    if (l == 0) red[w] = v;
    __syncthreads();                  // staging + red[] ready

    // coalesced uncached store: 160 consecutive u64 = block's 4 columns
    if (t < 49 && tid < 160){
      const unsigned long long* s64 = (const unsigned long long*)accL;
      unsigned long long* d64 = (unsigned long long*)((t&1) ? Xc1 : Xc0);
      __hip_atomic_store(&d64[160*p + tid], s64[tid], __ATOMIC_RELAXED, AGT);
    }
    float part = 0.f;
    if (tid == 0) part = ((red[0]+red[1])+(red[2]+red[3]))+red[4];   // > 0 always
    __syncthreads();                  // drains every wave's vmcnt before flag

    if (tid == 0)
      __hip_atomic_store(&flags[(t*PBLK+p)*FSTR], part, __ATOMIC_RELAXED, AGT);

    if (w == 0){
      // arrival + norm reduction in one round trip; padded slots + backoff
      float fv = 0.f;
      for (;;){
        if (l < PBLK && fv == 0.f)
          fv = __hip_atomic_load(&flags[(t*PBLK+l)*FSTR], __ATOMIC_RELAXED, AGT);
        if (__all((l >= PBLK) || (fv != 0.f))) break;
        __builtin_amdgcn_s_sleep(1);
      }
      float tot = wave_sum((l < PBLK) ? fv : 0.f);
      if (l == 0){
        red[5] = tot;                 // ||R_{t+1}||^2, deterministic order
        // one acquire -> buffer_inv of L1+L2; read side now refetches the
        // uncached X stores from the coherence point via cached loads
        (void)__hip_atomic_load(&flags[(t*PBLK)*FSTR], __ATOMIC_ACQUIRE, AGT);
      }
    }
    __syncthreads();                  // inv done; tot ready
    sc = 1.0f/sqrtf(red[5]);

    if (t < 49){
      // cached vectorized reload + LDS transpose (column-major -> row-major)
      const float4* X4 = (const float4*)((t&1) ? Xc1 : Xc0);
      for (int q = tid; q < 1600; q += TPB){
        float4 xv = X4[q];
        int a = q/20, i0 = 4*(q - a*20);
        Xs[(i0+0)*RP+a] = xv.x;
        Xs[(i0+1)*RP+a] = xv.y;
        Xs[(i0+2)*RP+a] = xv.z;
        Xs[(i0+3)*RP+a] = xv.w;
      }
    }
  }
  out[il*NN+al] = xn*sc;              // final normalization
}

extern "C" void kernel_launch(void* const* d_in, const int* in_sizes, int n_in,
                              void* d_out, int out_size, void* d_ws, size_t ws_size,
                              hipStream_t stream)
{
  (void)in_sizes; (void)n_in; (void)out_size; (void)ws_size;
  // zero barrier counter + 50*20 padded flag slots (ws re-poisoned each launch)
  hipMemsetAsync(d_ws, 0, (64 + 50*PBLK*FSTR)*4, stream);
  gvae_fused<<<PBLK, TPB, 0, stream>>>(
      (const float*)d_in[0],  (const int*)d_in[1],   (const int*)d_in[2],   (const float*)d_in[3],
      (const float*)d_in[4],  (const float*)d_in[5],  (const float*)d_in[6],  (const float*)d_in[7],
      (const float*)d_in[8],  (const float*)d_in[9],  (const float*)d_in[10], (const float*)d_in[11],
      (const float*)d_in[12], (const float*)d_in[13], (const float*)d_in[14], (const float*)d_in[15],
      (const float*)d_in[16], (const float*)d_in[17], (const float*)d_in[18], (const float*)d_in[19],
      (float*)d_out, (float*)d_ws);
}